// Round 1
// 174.665 us; speedup vs baseline: 1.0018x; 1.0018x over previous
//
#include <hip/hip_runtime.h>

// 2-level 2D Haar DWT, fused, FULL-GRID kernel (one 4x4 input tile per thread).
// x: (96, 512, 512) fp32. Previous persistent version (768 blocks, 8-image
// loop, depth-1 prefetch) was latency-bound at 12 waves/CU (Occupancy 20.9%,
// VALUBusy 5%, HBM 21-31%). This version launches 6144 blocks -> 8 blocks/CU
// = 32 waves/CU so wave-level TLP hides L3/HBM latency; no software pipeline
// needed. Out layout: a2,h2,v2,d2 (each 96*128*128), then h1,v1,d1
// (each 96*256*256). Arithmetic order identical to reference.

#define KINV 0.7071067811865476f

typedef float v4f __attribute__((ext_vector_type(4)));
typedef float v2f __attribute__((ext_vector_type(2)));

__global__ __launch_bounds__(256) void haar2_fused_kernel(
    const float* __restrict__ x, float* __restrict__ out, int nimg)
{
    const int tid = blockIdx.x * blockDim.x + threadIdx.x; // 0 .. nimg*16384-1
    const int c2  = tid & 127;          // level-2 col (lane-fast -> coalesced)
    const int r2  = (tid >> 7) & 127;   // level-2 row
    const int img = tid >> 14;          // 0..95

    const int row0 = r2 * 4;
    const int col0 = c2 * 4;

    // Section pointers.
    const size_t n2 = (size_t)nimg * 128 * 128;
    const size_t n1 = (size_t)nimg * 256 * 256;
    float* a2o = out;
    float* h2o = out + n2;
    float* v2o = out + 2 * n2;
    float* d2o = out + 3 * n2;
    float* h1o = out + 4 * n2;
    float* v1o = h1o + n1;
    float* d1o = h1o + 2 * n1;

    // Load the 4x4 tile: 4 x 16B per thread, 1KB contiguous per wave per row.
    const size_t in_base = (size_t)img * (512 * 512) + (size_t)row0 * 512 + col0;
    v4f b[4];
    #pragma unroll
    for (int k = 0; k < 4; ++k)
        b[k] = *reinterpret_cast<const v4f*>(x + in_base + (size_t)k * 512);

    float p[4][4];
    #pragma unroll
    for (int k = 0; k < 4; ++k) {
        p[k][0] = b[k].x; p[k][1] = b[k].y;
        p[k][2] = b[k].z; p[k][3] = b[k].w;
    }

    // Level 1: four 2x2 quads.
    float aa[2][2], da[2][2], ad[2][2], dd[2][2];
    #pragma unroll
    for (int i = 0; i < 2; ++i) {
        #pragma unroll
        for (int j = 0; j < 2; ++j) {
            const float p00 = p[2*i    ][2*j], p01 = p[2*i    ][2*j+1];
            const float p10 = p[2*i + 1][2*j], p11 = p[2*i + 1][2*j+1];
            // along W first, then along H — exact reference op order
            const float sA = (p00 + p01) * KINV;
            const float sB = (p10 + p11) * KINV;
            const float dA = (p00 - p01) * KINV;
            const float dB = (p10 - p11) * KINV;
            aa[i][j] = (sA + sB) * KINV;
            da[i][j] = (sA - sB) * KINV;   // cH1
            ad[i][j] = (dA + dB) * KINV;   // cV1
            dd[i][j] = (dA - dB) * KINV;   // cD1
        }
    }

    // Level-1 detail stores (float2/lane, coalesced across c2).
    const size_t img1 = (size_t)img * 256 * 256;
    #pragma unroll
    for (int i = 0; i < 2; ++i) {
        const size_t off = img1 + (size_t)(2 * r2 + i) * 256 + 2 * c2;
        *reinterpret_cast<v2f*>(h1o + off) = (v2f){da[i][0], da[i][1]};
        *reinterpret_cast<v2f*>(v1o + off) = (v2f){ad[i][0], ad[i][1]};
        *reinterpret_cast<v2f*>(d1o + off) = (v2f){dd[i][0], dd[i][1]};
    }

    // Level 2 from the aa quad.
    const float s0 = (aa[0][0] + aa[0][1]) * KINV;
    const float d0 = (aa[0][0] - aa[0][1]) * KINV;
    const float s1 = (aa[1][0] + aa[1][1]) * KINV;
    const float d1 = (aa[1][0] - aa[1][1]) * KINV;
    const size_t off2 = (size_t)img * 128 * 128 + (size_t)r2 * 128 + c2;
    a2o[off2] = (s0 + s1) * KINV;
    h2o[off2] = (s0 - s1) * KINV;
    v2o[off2] = (d0 + d1) * KINV;
    d2o[off2] = (d0 - d1) * KINV;
}

extern "C" void kernel_launch(void* const* d_in, const int* in_sizes, int n_in,
                              void* d_out, int out_size, void* d_ws, size_t ws_size,
                              hipStream_t stream) {
    const float* x = (const float*)d_in[0];
    float* out = (float*)d_out;
    const int nimg = in_sizes[0] / (512 * 512);        // 96
    const int total_threads = nimg * 128 * 128;        // 1,572,864 threads
    const int block = 256;
    const int grid = total_threads / block;            // 6144 blocks (8/CU resident)
    haar2_fused_kernel<<<grid, block, 0, stream>>>(x, out, nimg);
}